// Round 18
// baseline (628.111 us; speedup 1.0000x reference)
//
#include <hip/hip_runtime.h>

typedef __attribute__((ext_vector_type(8))) short short8;
typedef __attribute__((ext_vector_type(4))) float f32x4;

#define NN 100000
#define NE 600000
#define RR 128
#define HH 256
#define NB_SCAN 98     // ceil(NN/1024)
#define SEGB 16384     // per-seg LDS bytes (64 rows x 256B)

typedef const __attribute__((address_space(1))) void* gvp;
typedef __attribute__((address_space(3))) void* lvp;
typedef __attribute__((address_space(3))) char* lcp;

__device__ __forceinline__ unsigned short f2bf(float f) {
    unsigned u = __builtin_bit_cast(unsigned, f);
    u = (u + 0x7fffu + ((u >> 16) & 1u)) >> 16;   // RNE
    return (unsigned short)u;
}

// pack two f32 -> one dword of 2 bf16 (round-half-up), 3 VALU ops
__device__ __forceinline__ unsigned pkbf(float lo, float hi) {
    unsigned a = __builtin_bit_cast(unsigned, lo) + 0x8000u;
    unsigned b = __builtin_bit_cast(unsigned, hi) + 0x8000u;
    return __builtin_amdgcn_perm(b, a, 0x07060302);  // {b.hi16, a.hi16}
}

// LDS XOR swizzle: spread 16B blocks of a row across bank groups
__device__ __forceinline__ int swz(int byteoff, int row) {
    return byteoff ^ ((row & 7) << 4);
}

// pack one short8 MFMA A-fragment element group for weight matrix src[K][C]
// layout: dst[(tile*KS + ks)*64 + l][8] = src[ks*32+(l>>4)*8+j][tile*16+(l&15)]
__device__ __forceinline__ void packw(const float* __restrict__ src,
                                      unsigned short* __restrict__ dst,
                                      int KS, int C, int t) {
    int l = t & 63, ks = (t >> 6) % KS, tile = t / (64 * KS);
    int col = tile * 16 + (l & 15);
    int krow = ks * 32 + (l >> 4) * 8;
    uint4 u;
    u.x = pkbf(src[(krow + 0) * C + col], src[(krow + 1) * C + col]);
    u.y = pkbf(src[(krow + 2) * C + col], src[(krow + 3) * C + col]);
    u.z = pkbf(src[(krow + 4) * C + col], src[(krow + 5) * C + col]);
    u.w = pkbf(src[(krow + 6) * C + col], src[(krow + 7) * C + col]);
    *reinterpret_cast<uint4*>(dst + (size_t)t * 8) = u;
}

// ---- fused prep: 4 weight fragment-packs + node_rep bf16 cast ----
// blocks: [0,48) w1ep | [48,64) w2ep | [64,96) w1np | [96,112) w2np | [112,12612) nr16
__global__ __launch_bounds__(256) void prep_kernel(
    const float* __restrict__ W1e, const float* __restrict__ W2e,
    const float* __restrict__ W1n, const float* __restrict__ W2n,
    const float* __restrict__ node_rep,
    unsigned short* __restrict__ w1ep, unsigned short* __restrict__ w2ep,
    unsigned short* __restrict__ w1np, unsigned short* __restrict__ w2np,
    unsigned short* __restrict__ nr16)
{
    const int b = blockIdx.x;
    if (b >= 112) {
        int i = (b - 112) * 256 + threadIdx.x;      // 4 floats per thread
        if (i < NN * RR / 4) {
            float4 v = *reinterpret_cast<const float4*>(node_rep + (size_t)i * 4);
            uint2 u;
            u.x = pkbf(v.x, v.y);
            u.y = pkbf(v.z, v.w);
            *reinterpret_cast<uint2*>(nr16 + (size_t)i * 4) = u;
        }
        return;
    }
    if (b < 48)      { packw(W1e, w1ep, 12, 256, b * 256 + threadIdx.x); }          // 16 tiles x 12 ks
    else if (b < 64) { packw(W2e, w2ep,  8, 128, (b - 48) * 256 + threadIdx.x); }   // 8 tiles x 8 ks
    else if (b < 96) { packw(W1n, w1np,  8, 256, (b - 64) * 256 + threadIdx.x); }   // 16 tiles x 8 ks
    else             { packw(W2n, w2np,  8, 128, (b - 96) * 256 + threadIdx.x); }   // 8 tiles x 8 ks
}

// ---------------- CSR build ----------------
__global__ __launch_bounds__(256) void count_kernel(const int* __restrict__ esrc,
                                                    const int* __restrict__ edst,
                                                    int* __restrict__ cnt) {
    int i = blockIdx.x * 256 + threadIdx.x;
    if (i < NE) {
        atomicAdd(&cnt[esrc[i]], 1);
        atomicAdd(&cnt[edst[i]], 1);
    }
}

__global__ __launch_bounds__(1024) void scan_part(const int* __restrict__ cnt,
                                                  int* __restrict__ excl,
                                                  int* __restrict__ bsum) {
    __shared__ int wsum[16];
    const int tid = threadIdx.x;
    const int lane = tid & 63, w = tid >> 6;
    int i = blockIdx.x * 1024 + tid;
    int v = (i < NN) ? cnt[i] : 0;
    int s = v;
    #pragma unroll
    for (int d = 1; d < 64; d <<= 1) {
        int t = __shfl_up(s, d, 64);
        if (lane >= d) s += t;
    }
    if (lane == 63) wsum[w] = s;
    __syncthreads();
    if (w == 0) {
        int x = (lane < 16) ? wsum[lane] : 0;
        int sx = x;
        #pragma unroll
        for (int d = 1; d < 16; d <<= 1) {
            int t = __shfl_up(sx, d, 64);
            if (lane >= d) sx += t;
        }
        if (lane < 16) wsum[lane] = sx - x;          // exclusive wave offset
        if (lane == 15) bsum[blockIdx.x] = sx;       // block total
    }
    __syncthreads();
    if (i < NN) excl[i] = wsum[w] + (s - v);
}

__global__ void scan_tops(int* __restrict__ bsum, int* __restrict__ offs_nn) {
    if (threadIdx.x == 0) {
        int run = 0;
        for (int b = 0; b < NB_SCAN; ++b) { int t = bsum[b]; bsum[b] = run; run += t; }
        *offs_nn = run;   // offs[NN] = 2*NE
    }
}

__global__ __launch_bounds__(1024) void scan_add(int* __restrict__ offs,
                                                 const int* __restrict__ bsum,
                                                 int* __restrict__ cur) {
    int i = blockIdx.x * 1024 + threadIdx.x;
    if (i < NN) { int v = offs[i] + bsum[blockIdx.x]; offs[i] = v; cur[i] = v; }
}

__global__ __launch_bounds__(256) void fill_kernel(const int* __restrict__ esrc,
                                                   const int* __restrict__ edst,
                                                   int* __restrict__ cur,
                                                   int* __restrict__ adj) {
    int i = blockIdx.x * 256 + threadIdx.x;
    if (i < NE) {
        int p = atomicAdd(&cur[esrc[i]], 1);
        adj[p] = i;
        int q = atomicAdd(&cur[edst[i]], 1);
        adj[q] = i;
    }
}

// ---- edge kernel: tri-buffer DMA + packed weights (R16 config: (512,5), no spill) ----
__global__ __launch_bounds__(512, 5) void edge_kernel(
    const unsigned short* __restrict__ nr16, const float* __restrict__ edge_attr,
    const int* __restrict__ esrc, const int* __restrict__ edst,
    const unsigned short* __restrict__ w1p, const float* __restrict__ b1,
    const unsigned short* __restrict__ w2p, const float* __restrict__ b2,
    float* __restrict__ edge_out)
{
    __shared__ char Sbuf[3 * SEGB];   // S0,S1,S2; H (32KB) aliases S0+S1
    lcp SbufL = (lcp)Sbuf;
    const int tid = threadIdx.x;
    const int e0 = blockIdx.x * 64;
    const int lane = tid & 63, wave = tid >> 6;
    const int l15 = lane & 15, l4 = lane >> 4;

    // segA staging: 512 threads cover 64 rows x 32 float4
    const int c4 = tid & 31;
    const int row_b = tid >> 5;           // add j*16

    // ---- issue segA f32 loads FIRST (pack waits at vmcnt(#DMA), not 0) ----
    float4 ga[4];
    #pragma unroll
    for (int j = 0; j < 4; ++j) {
        int row = row_b + j * 16;
        ga[j] = *reinterpret_cast<const float4*>(edge_attr + (size_t)(e0 + row) * RR + c4 * 4);
    }

    // ---- issue segB DMA -> S1 and segC DMA -> S2 (both up front) ----
    {
        int r0 = wave * 8 + (lane >> 4);
        int r1 = r0 + 4;
        int i0 = esrc[e0 + r0];
        int i1 = esrc[e0 + r1];
        int j0 = edst[e0 + r0];
        int j1 = edst[e0 + r1];
        const char* gs0 = (const char*)nr16 + (size_t)i0 * 256 + (((lane & 15) ^ (r0 & 7)) << 4);
        const char* gs1 = (const char*)nr16 + (size_t)i1 * 256 + (((lane & 15) ^ (r1 & 7)) << 4);
        const char* gd0 = (const char*)nr16 + (size_t)j0 * 256 + (((lane & 15) ^ (r0 & 7)) << 4);
        const char* gd1 = (const char*)nr16 + (size_t)j1 * 256 + (((lane & 15) ^ (r1 & 7)) << 4);
        __builtin_amdgcn_global_load_lds((gvp)gs0, (lvp)(SbufL + SEGB + wave * 2048), 16, 0, 0);
        __builtin_amdgcn_global_load_lds((gvp)gs1, (lvp)(SbufL + SEGB + wave * 2048 + 1024), 16, 0, 0);
        __builtin_amdgcn_global_load_lds((gvp)gd0, (lvp)(SbufL + 2 * SEGB + wave * 2048), 16, 0, 0);
        __builtin_amdgcn_global_load_lds((gvp)gd1, (lvp)(SbufL + 2 * SEGB + wave * 2048 + 1024), 16, 0, 0);
    }

    // ---- pack segA -> S0 ----
    #pragma unroll
    for (int j = 0; j < 4; ++j) {
        int row = row_b + j * 16;
        uint2 u; u.x = pkbf(ga[j].x, ga[j].y); u.y = pkbf(ga[j].z, ga[j].w);
        *reinterpret_cast<uint2*>(&Sbuf[swz(row * 256 + c4 * 8, row)]) = u;
    }
    __syncthreads();   // single drain: S0/S1/S2 all ready

    f32x4 acc[2][4] = {};
    // wave's W1 fragment base: tiles 2*wave, 2*wave+1 of 16; 12 ksteps each
    const unsigned short* w1base = w1p + ((size_t)(2 * wave) * 12 * 64 + lane) * 8;

#define GEMM1_SEG(SEGIDX, SBASE)                                                     \
    _Pragma("unroll")                                                                \
    for (int kk2 = 0; kk2 < 4; ++kk2) {                                              \
        const int koel = kk2 * 32 + l4 * 8;                                          \
        short8 bfr[4];                                                               \
        _Pragma("unroll")                                                            \
        for (int et = 0; et < 4; ++et) {                                             \
            int rw = et * 16 + l15;                                                  \
            bfr[et] = *reinterpret_cast<const short8*>(                              \
                &Sbuf[(SBASE) + swz(rw * 256 + koel * 2, rw)]);                      \
        }                                                                            \
        _Pragma("unroll")                                                            \
        for (int ht = 0; ht < 2; ++ht) {                                             \
            short8 afr = *reinterpret_cast<const short8*>(                           \
                w1base + (size_t)(ht * 12 + (SEGIDX) * 4 + kk2) * 64 * 8);           \
            _Pragma("unroll")                                                        \
            for (int et = 0; et < 4; ++et)                                           \
                acc[ht][et] = __builtin_amdgcn_mfma_f32_16x16x32_bf16(               \
                    afr, bfr[et], acc[ht][et], 0, 0, 0);                             \
        }                                                                            \
    }

    // ---- GEMM1: all three segments, no intervening barriers ----
    GEMM1_SEG(0, 0)
    GEMM1_SEG(1, SEGB)
    GEMM1_SEG(2, 2 * SEGB)
    __syncthreads();   // all A reads done; alias H over S0+S1
#undef GEMM1_SEG

    // ---- H = relu(acc + b1) -> bf16 LDS (row stride 512B, swizzled) ----
    const int hbase = wave * 32;
    #pragma unroll
    for (int ht = 0; ht < 2; ++ht) {
        const int h0 = hbase + ht * 16 + l4 * 4;
        float4 bb = *reinterpret_cast<const float4*>(b1 + h0);
        #pragma unroll
        for (int et = 0; et < 4; ++et) {
            int e = et * 16 + l15;
            float x0 = fmaxf(acc[ht][et][0] + bb.x, 0.f);
            float x1 = fmaxf(acc[ht][et][1] + bb.y, 0.f);
            float x2 = fmaxf(acc[ht][et][2] + bb.z, 0.f);
            float x3 = fmaxf(acc[ht][et][3] + bb.w, 0.f);
            uint2 u; u.x = pkbf(x0, x1); u.y = pkbf(x2, x3);
            *reinterpret_cast<uint2*>(&Sbuf[swz(e * 512 + h0 * 2, e)]) = u;
        }
    }
    __syncthreads();   // H ready

    // ---- GEMM2': D2'[c][e] = sum_h W2T[c][h] * H[e][h] ----
    f32x4 acc2[4] = {};
    const unsigned short* w2base = w2p + ((size_t)(wave * 8) * 64 + lane) * 8;
    #pragma unroll
    for (int ks = 0; ks < 8; ++ks) {
        const int koel = ks * 32 + l4 * 8;
        short8 afr = *reinterpret_cast<const short8*>(w2base + (size_t)ks * 64 * 8);
        #pragma unroll
        for (int et = 0; et < 4; ++et) {
            int rw = et * 16 + l15;
            short8 bfr = *reinterpret_cast<const short8*>(&Sbuf[swz(rw * 512 + koel * 2, rw)]);
            acc2[et] = __builtin_amdgcn_mfma_f32_16x16x32_bf16(afr, bfr, acc2[et], 0, 0, 0);
        }
    }

    // ---- epilogue: bias + store edge_out ----
    {
        const int c0 = wave * 16 + l4 * 4;
        float4 bb = *reinterpret_cast<const float4*>(b2 + c0);
        #pragma unroll
        for (int et = 0; et < 4; ++et) {
            int e = et * 16 + l15;
            float4 v;
            v.x = acc2[et][0] + bb.x;
            v.y = acc2[et][1] + bb.y;
            v.z = acc2[et][2] + bb.z;
            v.w = acc2[et][3] + bb.w;
            *reinterpret_cast<float4*>(edge_out + (size_t)(e0 + e) * RR + c0) = v;
        }
    }
}

// ---- node kernel: CSR pull + MLP, packed weights, merged accu pool, bf16 staging ----
__global__ __launch_bounds__(512, 6) void node_kernel(
    const unsigned short* __restrict__ nr16,
    const int* __restrict__ offs, const int* __restrict__ adj,
    const float* __restrict__ edge_out,
    const unsigned short* __restrict__ w1p, const float* __restrict__ b1,
    const unsigned short* __restrict__ w2p, const float* __restrict__ b2,
    float* __restrict__ out)
{
    __shared__ char Abuf[64 * 512];   // A-tile (256 bf16/row); H aliases after GEMM1
    const int tid = threadIdx.x;
    const int n0 = blockIdx.x * 64;
    const int r = tid >> 3, t8 = tid & 7;     // 8 threads/row, 16 elements each
    const int n = n0 + r;
    const int nc = (n < NN) ? n : NN - 1;

    // nr16 -> A cols [t8*16, +16)  (bf16 direct copy, no conversion)
    {
        const uint4* src = reinterpret_cast<const uint4*>(nr16 + (size_t)nc * RR + t8 * 16);
        uint4 v0 = src[0], v1 = src[1];
        int b = r * 512 + t8 * 32;
        *reinterpret_cast<uint2*>(&Abuf[swz(b, r)])      = uint2{v0.x, v0.y};
        *reinterpret_cast<uint2*>(&Abuf[swz(b + 8, r)])  = uint2{v0.z, v0.w};
        *reinterpret_cast<uint2*>(&Abuf[swz(b + 16, r)]) = uint2{v1.x, v1.y};
        *reinterpret_cast<uint2*>(&Abuf[swz(b + 24, r)]) = uint2{v1.z, v1.w};
    }
    // e2n: f32 gather-sum (4-way unrolled) -> A cols [128+t8*16, +16)
    {
        f32x4 a0 = {}, a1 = {}, a2 = {}, a3 = {};
        if (n < NN) {
            int p = offs[n];
            const int pe = offs[n + 1];
            for (; p + 3 < pe; p += 4) {
                int ea = adj[p], eb = adj[p + 1], ec = adj[p + 2], ed = adj[p + 3];
                const f32x4* ra = reinterpret_cast<const f32x4*>(edge_out + (size_t)ea * RR + t8 * 16);
                const f32x4* rb = reinterpret_cast<const f32x4*>(edge_out + (size_t)eb * RR + t8 * 16);
                const f32x4* rc = reinterpret_cast<const f32x4*>(edge_out + (size_t)ec * RR + t8 * 16);
                const f32x4* rd = reinterpret_cast<const f32x4*>(edge_out + (size_t)ed * RR + t8 * 16);
                a0 += ra[0]; a1 += ra[1]; a2 += ra[2]; a3 += ra[3];
                a0 += rb[0]; a1 += rb[1]; a2 += rb[2]; a3 += rb[3];
                a0 += rc[0]; a1 += rc[1]; a2 += rc[2]; a3 += rc[3];
                a0 += rd[0]; a1 += rd[1]; a2 += rd[2]; a3 += rd[3];
            }
            for (; p < pe; ++p) {
                int e = adj[p];
                const f32x4* rr = reinterpret_cast<const f32x4*>(edge_out + (size_t)e * RR + t8 * 16);
                a0 += rr[0]; a1 += rr[1]; a2 += rr[2]; a3 += rr[3];
            }
        }
        uint2 u;
        int b = r * 512 + 256 + t8 * 32;
        u.x = pkbf(a0[0], a0[1]); u.y = pkbf(a0[2], a0[3]);
        *reinterpret_cast<uint2*>(&Abuf[swz(b, r)]) = u;
        u.x = pkbf(a1[0], a1[1]); u.y = pkbf(a1[2], a1[3]);
        *reinterpret_cast<uint2*>(&Abuf[swz(b + 8, r)]) = u;
        u.x = pkbf(a2[0], a2[1]); u.y = pkbf(a2[2], a2[3]);
        *reinterpret_cast<uint2*>(&Abuf[swz(b + 16, r)]) = u;
        u.x = pkbf(a3[0], a3[1]); u.y = pkbf(a3[2], a3[3]);
        *reinterpret_cast<uint2*>(&Abuf[swz(b + 24, r)]) = u;
    }
    __syncthreads();

    const int lane = tid & 63, wave = tid >> 6;
    const int l15 = lane & 15, l4 = lane >> 4;

    // GEMM1: k = 256, 8 ksteps; merged pool accu[0..7]; GEMM2 reuses accu[0..3]
    f32x4 accu[8] = {};
    const unsigned short* w1base = w1p + ((size_t)(2 * wave) * 8 * 64 + lane) * 8;
    #pragma unroll
    for (int kk = 0; kk < 8; ++kk) {
        const int koel = kk * 32 + l4 * 8;
        short8 bfr[4];
        #pragma unroll
        for (int et = 0; et < 4; ++et) {
            int rw = et * 16 + l15;
            bfr[et] = *reinterpret_cast<const short8*>(&Abuf[swz(rw * 512 + koel * 2, rw)]);
        }
        #pragma unroll
        for (int ht = 0; ht < 2; ++ht) {
            short8 afr = *reinterpret_cast<const short8*>(
                w1base + (size_t)(ht * 8 + kk) * 64 * 8);
            #pragma unroll
            for (int et = 0; et < 4; ++et)
                accu[ht * 4 + et] = __builtin_amdgcn_mfma_f32_16x16x32_bf16(afr, bfr[et], accu[ht * 4 + et], 0, 0, 0);
        }
    }
    __syncthreads();   // A reads done; alias H

    const int hbase = wave * 32;
    #pragma unroll
    for (int ht = 0; ht < 2; ++ht) {
        const int h0 = hbase + ht * 16 + l4 * 4;
        float4 bb = *reinterpret_cast<const float4*>(b1 + h0);
        #pragma unroll
        for (int et = 0; et < 4; ++et) {
            int e = et * 16 + l15;
            float x0 = fmaxf(accu[ht * 4 + et][0] + bb.x, 0.f);
            float x1 = fmaxf(accu[ht * 4 + et][1] + bb.y, 0.f);
            float x2 = fmaxf(accu[ht * 4 + et][2] + bb.z, 0.f);
            float x3 = fmaxf(accu[ht * 4 + et][3] + bb.w, 0.f);
            uint2 u; u.x = pkbf(x0, x1); u.y = pkbf(x2, x3);
            *reinterpret_cast<uint2*>(&Abuf[swz(e * 512 + h0 * 2, e)]) = u;
        }
    }
    __syncthreads();

    #pragma unroll
    for (int et = 0; et < 4; ++et) accu[et] = f32x4{0.f, 0.f, 0.f, 0.f};

    // GEMM2: 8 ksteps; wave's c-tile = wave
    const unsigned short* w2base = w2p + ((size_t)(wave * 8) * 64 + lane) * 8;
    #pragma unroll
    for (int ks = 0; ks < 8; ++ks) {
        const int koel = ks * 32 + l4 * 8;
        short8 afr = *reinterpret_cast<const short8*>(w2base + (size_t)ks * 64 * 8);
        #pragma unroll
        for (int et = 0; et < 4; ++et) {
            int rw = et * 16 + l15;
            short8 bfr = *reinterpret_cast<const short8*>(&Abuf[swz(rw * 512 + koel * 2, rw)]);
            accu[et] = __builtin_amdgcn_mfma_f32_16x16x32_bf16(afr, bfr, accu[et], 0, 0, 0);
        }
    }

    {
        const int c0 = wave * 16 + l4 * 4;
        float4 bb = *reinterpret_cast<const float4*>(b2 + c0);
        #pragma unroll
        for (int et = 0; et < 4; ++et) {
            int nn2 = n0 + et * 16 + l15;
            if (nn2 < NN) {
                float4 v;
                v.x = accu[et][0] + bb.x;
                v.y = accu[et][1] + bb.y;
                v.z = accu[et][2] + bb.z;
                v.w = accu[et][3] + bb.w;
                *reinterpret_cast<float4*>(out + (size_t)nn2 * RR + c0) = v;
            }
        }
    }
}

extern "C" void kernel_launch(void* const* d_in, const int* in_sizes, int n_in,
                              void* d_out, int out_size, void* d_ws, size_t ws_size,
                              hipStream_t stream) {
    const float* node_rep  = (const float*)d_in[0];
    const float* edge_attr = (const float*)d_in[1];
    const int*   esrc      = (const int*)d_in[2];
    const int*   edst      = (const int*)d_in[3];
    const float* W1e = (const float*)d_in[4];
    const float* b1e = (const float*)d_in[5];
    const float* W2e = (const float*)d_in[6];
    const float* b2e = (const float*)d_in[7];
    const float* W1n = (const float*)d_in[8];
    const float* b1n = (const float*)d_in[9];
    const float* W2n = (const float*)d_in[10];
    const float* b2n = (const float*)d_in[11];

    float* out      = (float*)d_out;
    float* node_out = out;                          // N*R
    float* edge_out = out + (size_t)NN * RR;        // E*R

    // workspace layout (bytes)
    char* ws = (char*)d_ws;
    unsigned short* w1ep = (unsigned short*)ws;                 // 98304 shorts
    unsigned short* w2ep = w1ep + 98304;                        // 32768
    unsigned short* w1np = w2ep + 32768;                        // 65536
    unsigned short* w2np = w1np + 65536;                        // 32768
    size_t off = 458752;
    unsigned short* nr16 = (unsigned short*)(ws + off); off += (size_t)NN * RR * 2;  // 25.6 MB
    int* cnt  = (int*)(ws + off);               off += 400000;  // [NN] (fill cursor)
    int* offs = (int*)(ws + off);               off += 400008;  // [NN+1]
    int* adj  = (int*)(ws + off);               off += 4800000; // [2*NE]
    int* bsum = (int*)(ws + off);               off += 512;     // [NB_SCAN]

    hipMemsetAsync(cnt, 0, (size_t)NN * sizeof(int), stream);

    prep_kernel<<<12612, 256, 0, stream>>>(W1e, W2e, W1n, W2n, node_rep,
                                           w1ep, w2ep, w1np, w2np, nr16);

    count_kernel<<<(NE + 255) / 256, 256, 0, stream>>>(esrc, edst, cnt);
    scan_part<<<NB_SCAN, 1024, 0, stream>>>(cnt, offs, bsum);
    scan_tops<<<1, 64, 0, stream>>>(bsum, offs + NN);
    scan_add<<<NB_SCAN, 1024, 0, stream>>>(offs, bsum, cnt);
    fill_kernel<<<(NE + 255) / 256, 256, 0, stream>>>(esrc, edst, cnt, adj);

    edge_kernel<<<NE / 64, 512, 0, stream>>>(nr16, edge_attr, esrc, edst,
                                             w1ep, b1e, w2ep, b2e, edge_out);

    node_kernel<<<(NN + 63) / 64, 512, 0, stream>>>(nr16, offs, adj, edge_out,
                                                    w1np, b1n, w2np, b2n, node_out);
}

// Round 20
// 587.252 us; speedup vs baseline: 1.0696x; 1.0696x over previous
//
#include <hip/hip_runtime.h>

typedef __attribute__((ext_vector_type(8))) short short8;
typedef __attribute__((ext_vector_type(4))) float f32x4;

#define NN 100000
#define NE 600000
#define RR 128
#define HH 256
#define NB_SCAN 98     // ceil(NN/1024)
#define SEGB 16384     // per-seg LDS bytes (64 rows x 256B)

typedef const __attribute__((address_space(1))) void* gvp;
typedef __attribute__((address_space(3))) void* lvp;
typedef __attribute__((address_space(3))) char* lcp;

__device__ __forceinline__ unsigned short f2bf(float f) {
    unsigned u = __builtin_bit_cast(unsigned, f);
    u = (u + 0x7fffu + ((u >> 16) & 1u)) >> 16;   // RNE
    return (unsigned short)u;
}

// pack two f32 -> one dword of 2 bf16 (round-half-up), 3 VALU ops
__device__ __forceinline__ unsigned pkbf(float lo, float hi) {
    unsigned a = __builtin_bit_cast(unsigned, lo) + 0x8000u;
    unsigned b = __builtin_bit_cast(unsigned, hi) + 0x8000u;
    return __builtin_amdgcn_perm(b, a, 0x07060302);  // {b.hi16, a.hi16}
}
__device__ __forceinline__ float bflo(unsigned u) {
    return __builtin_bit_cast(float, u << 16);
}
__device__ __forceinline__ float bfhi(unsigned u) {
    return __builtin_bit_cast(float, u & 0xffff0000u);
}

// LDS XOR swizzle: spread 16B blocks of a row across bank groups
__device__ __forceinline__ int swz(int byteoff, int row) {
    return byteoff ^ ((row & 7) << 4);
}

// pack one short8 MFMA A-fragment element group for weight matrix src[K][C]
// layout: dst[(tile*KS + ks)*64 + l][8] = src[ks*32+(l>>4)*8+j][tile*16+(l&15)]
__device__ __forceinline__ void packw(const float* __restrict__ src,
                                      unsigned short* __restrict__ dst,
                                      int KS, int C, int t) {
    int l = t & 63, ks = (t >> 6) % KS, tile = t / (64 * KS);
    int col = tile * 16 + (l & 15);
    int krow = ks * 32 + (l >> 4) * 8;
    uint4 u;
    u.x = pkbf(src[(krow + 0) * C + col], src[(krow + 1) * C + col]);
    u.y = pkbf(src[(krow + 2) * C + col], src[(krow + 3) * C + col]);
    u.z = pkbf(src[(krow + 4) * C + col], src[(krow + 5) * C + col]);
    u.w = pkbf(src[(krow + 6) * C + col], src[(krow + 7) * C + col]);
    *reinterpret_cast<uint4*>(dst + (size_t)t * 8) = u;
}

// ---- fused prep: 4 weight fragment-packs + node_rep bf16 cast ----
// blocks: [0,48) w1ep | [48,64) w2ep | [64,96) w1np | [96,112) w2np | [112,12612) nr16
__global__ __launch_bounds__(256) void prep_kernel(
    const float* __restrict__ W1e, const float* __restrict__ W2e,
    const float* __restrict__ W1n, const float* __restrict__ W2n,
    const float* __restrict__ node_rep,
    unsigned short* __restrict__ w1ep, unsigned short* __restrict__ w2ep,
    unsigned short* __restrict__ w1np, unsigned short* __restrict__ w2np,
    unsigned short* __restrict__ nr16)
{
    const int b = blockIdx.x;
    if (b >= 112) {
        int i = (b - 112) * 256 + threadIdx.x;      // 4 floats per thread
        if (i < NN * RR / 4) {
            float4 v = *reinterpret_cast<const float4*>(node_rep + (size_t)i * 4);
            uint2 u;
            u.x = pkbf(v.x, v.y);
            u.y = pkbf(v.z, v.w);
            *reinterpret_cast<uint2*>(nr16 + (size_t)i * 4) = u;
        }
        return;
    }
    if (b < 48)      { packw(W1e, w1ep, 12, 256, b * 256 + threadIdx.x); }          // 16 tiles x 12 ks
    else if (b < 64) { packw(W2e, w2ep,  8, 128, (b - 48) * 256 + threadIdx.x); }   // 8 tiles x 8 ks
    else if (b < 96) { packw(W1n, w1np,  8, 256, (b - 64) * 256 + threadIdx.x); }   // 16 tiles x 8 ks
    else             { packw(W2n, w2np,  8, 128, (b - 96) * 256 + threadIdx.x); }   // 8 tiles x 8 ks
}

// ---------------- CSR build ----------------
__global__ __launch_bounds__(256) void count_kernel(const int* __restrict__ esrc,
                                                    const int* __restrict__ edst,
                                                    int* __restrict__ cnt) {
    int i = blockIdx.x * 256 + threadIdx.x;
    if (i < NE) {
        atomicAdd(&cnt[esrc[i]], 1);
        atomicAdd(&cnt[edst[i]], 1);
    }
}

__global__ __launch_bounds__(1024) void scan_part(const int* __restrict__ cnt,
                                                  int* __restrict__ excl,
                                                  int* __restrict__ bsum) {
    __shared__ int wsum[16];
    const int tid = threadIdx.x;
    const int lane = tid & 63, w = tid >> 6;
    int i = blockIdx.x * 1024 + tid;
    int v = (i < NN) ? cnt[i] : 0;
    int s = v;
    #pragma unroll
    for (int d = 1; d < 64; d <<= 1) {
        int t = __shfl_up(s, d, 64);
        if (lane >= d) s += t;
    }
    if (lane == 63) wsum[w] = s;
    __syncthreads();
    if (w == 0) {
        int x = (lane < 16) ? wsum[lane] : 0;
        int sx = x;
        #pragma unroll
        for (int d = 1; d < 16; d <<= 1) {
            int t = __shfl_up(sx, d, 64);
            if (lane >= d) sx += t;
        }
        if (lane < 16) wsum[lane] = sx - x;          // exclusive wave offset
        if (lane == 15) bsum[blockIdx.x] = sx;       // block total
    }
    __syncthreads();
    if (i < NN) excl[i] = wsum[w] + (s - v);
}

__global__ void scan_tops(int* __restrict__ bsum, int* __restrict__ offs_nn) {
    if (threadIdx.x == 0) {
        int run = 0;
        for (int b = 0; b < NB_SCAN; ++b) { int t = bsum[b]; bsum[b] = run; run += t; }
        *offs_nn = run;   // offs[NN] = 2*NE
    }
}

__global__ __launch_bounds__(1024) void scan_add(int* __restrict__ offs,
                                                 const int* __restrict__ bsum,
                                                 int* __restrict__ cur) {
    int i = blockIdx.x * 1024 + threadIdx.x;
    if (i < NN) { int v = offs[i] + bsum[blockIdx.x]; offs[i] = v; cur[i] = v; }
}

__global__ __launch_bounds__(256) void fill_kernel(const int* __restrict__ esrc,
                                                   const int* __restrict__ edst,
                                                   int* __restrict__ cur,
                                                   int* __restrict__ adj) {
    int i = blockIdx.x * 256 + threadIdx.x;
    if (i < NE) {
        int p = atomicAdd(&cur[esrc[i]], 1);
        adj[p] = i;
        int q = atomicAdd(&cur[edst[i]], 1);
        adj[q] = i;
    }
}

// ---- edge kernel: tri-buffer DMA + packed weights + full-line bf16 mirror ----
__global__ __launch_bounds__(512, 5) void edge_kernel(
    const unsigned short* __restrict__ nr16, const float* __restrict__ edge_attr,
    const int* __restrict__ esrc, const int* __restrict__ edst,
    const unsigned short* __restrict__ w1p, const float* __restrict__ b1,
    const unsigned short* __restrict__ w2p, const float* __restrict__ b2,
    float* __restrict__ edge_out, unsigned short* __restrict__ eo16)
{
    __shared__ char Sbuf[3 * SEGB];   // S0,S1,S2; H (32KB) aliases S0+S1
    lcp SbufL = (lcp)Sbuf;
    const int tid = threadIdx.x;
    const int e0 = blockIdx.x * 64;
    const int lane = tid & 63, wave = tid >> 6;
    const int l15 = lane & 15, l4 = lane >> 4;

    // segA staging: 512 threads cover 64 rows x 32 float4
    const int c4 = tid & 31;
    const int row_b = tid >> 5;           // add j*16

    // ---- issue segA f32 loads FIRST (pack waits at vmcnt(#DMA), not 0) ----
    float4 ga[4];
    #pragma unroll
    for (int j = 0; j < 4; ++j) {
        int row = row_b + j * 16;
        ga[j] = *reinterpret_cast<const float4*>(edge_attr + (size_t)(e0 + row) * RR + c4 * 4);
    }

    // ---- issue segB DMA -> S1 and segC DMA -> S2 (both up front) ----
    {
        int r0 = wave * 8 + (lane >> 4);
        int r1 = r0 + 4;
        int i0 = esrc[e0 + r0];
        int i1 = esrc[e0 + r1];
        int j0 = edst[e0 + r0];
        int j1 = edst[e0 + r1];
        const char* gs0 = (const char*)nr16 + (size_t)i0 * 256 + (((lane & 15) ^ (r0 & 7)) << 4);
        const char* gs1 = (const char*)nr16 + (size_t)i1 * 256 + (((lane & 15) ^ (r1 & 7)) << 4);
        const char* gd0 = (const char*)nr16 + (size_t)j0 * 256 + (((lane & 15) ^ (r0 & 7)) << 4);
        const char* gd1 = (const char*)nr16 + (size_t)j1 * 256 + (((lane & 15) ^ (r1 & 7)) << 4);
        __builtin_amdgcn_global_load_lds((gvp)gs0, (lvp)(SbufL + SEGB + wave * 2048), 16, 0, 0);
        __builtin_amdgcn_global_load_lds((gvp)gs1, (lvp)(SbufL + SEGB + wave * 2048 + 1024), 16, 0, 0);
        __builtin_amdgcn_global_load_lds((gvp)gd0, (lvp)(SbufL + 2 * SEGB + wave * 2048), 16, 0, 0);
        __builtin_amdgcn_global_load_lds((gvp)gd1, (lvp)(SbufL + 2 * SEGB + wave * 2048 + 1024), 16, 0, 0);
    }

    // ---- pack segA -> S0 ----
    #pragma unroll
    for (int j = 0; j < 4; ++j) {
        int row = row_b + j * 16;
        uint2 u; u.x = pkbf(ga[j].x, ga[j].y); u.y = pkbf(ga[j].z, ga[j].w);
        *reinterpret_cast<uint2*>(&Sbuf[swz(row * 256 + c4 * 8, row)]) = u;
    }
    __syncthreads();   // single drain: S0/S1/S2 all ready

    f32x4 acc[2][4] = {};
    // wave's W1 fragment base: tiles 2*wave, 2*wave+1 of 16; 12 ksteps each
    const unsigned short* w1base = w1p + ((size_t)(2 * wave) * 12 * 64 + lane) * 8;

#define GEMM1_SEG(SEGIDX, SBASE)                                                     \
    _Pragma("unroll")                                                                \
    for (int kk2 = 0; kk2 < 4; ++kk2) {                                              \
        const int koel = kk2 * 32 + l4 * 8;                                          \
        short8 bfr[4];                                                               \
        _Pragma("unroll")                                                            \
        for (int et = 0; et < 4; ++et) {                                             \
            int rw = et * 16 + l15;                                                  \
            bfr[et] = *reinterpret_cast<const short8*>(                              \
                &Sbuf[(SBASE) + swz(rw * 256 + koel * 2, rw)]);                      \
        }                                                                            \
        _Pragma("unroll")                                                            \
        for (int ht = 0; ht < 2; ++ht) {                                             \
            short8 afr = *reinterpret_cast<const short8*>(                           \
                w1base + (size_t)(ht * 12 + (SEGIDX) * 4 + kk2) * 64 * 8);           \
            _Pragma("unroll")                                                        \
            for (int et = 0; et < 4; ++et)                                           \
                acc[ht][et] = __builtin_amdgcn_mfma_f32_16x16x32_bf16(               \
                    afr, bfr[et], acc[ht][et], 0, 0, 0);                             \
        }                                                                            \
    }

    // ---- GEMM1: all three segments, no intervening barriers ----
    GEMM1_SEG(0, 0)
    GEMM1_SEG(1, SEGB)
    GEMM1_SEG(2, 2 * SEGB)
    __syncthreads();   // all A reads done; alias H over S0+S1
#undef GEMM1_SEG

    // ---- H = relu(acc + b1) -> bf16 LDS (row stride 512B, swizzled) ----
    const int hbase = wave * 32;
    #pragma unroll
    for (int ht = 0; ht < 2; ++ht) {
        const int h0 = hbase + ht * 16 + l4 * 4;
        float4 bb = *reinterpret_cast<const float4*>(b1 + h0);
        #pragma unroll
        for (int et = 0; et < 4; ++et) {
            int e = et * 16 + l15;
            float x0 = fmaxf(acc[ht][et][0] + bb.x, 0.f);
            float x1 = fmaxf(acc[ht][et][1] + bb.y, 0.f);
            float x2 = fmaxf(acc[ht][et][2] + bb.z, 0.f);
            float x3 = fmaxf(acc[ht][et][3] + bb.w, 0.f);
            uint2 u; u.x = pkbf(x0, x1); u.y = pkbf(x2, x3);
            *reinterpret_cast<uint2*>(&Sbuf[swz(e * 512 + h0 * 2, e)]) = u;
        }
    }
    __syncthreads();   // H ready

    // ---- GEMM2': D2'[c][e] = sum_h W2T[c][h] * H[e][h] ----
    f32x4 acc2[4] = {};
    const unsigned short* w2base = w2p + ((size_t)(wave * 8) * 64 + lane) * 8;
    #pragma unroll
    for (int ks = 0; ks < 8; ++ks) {
        const int koel = ks * 32 + l4 * 8;
        short8 afr = *reinterpret_cast<const short8*>(w2base + (size_t)ks * 64 * 8);
        #pragma unroll
        for (int et = 0; et < 4; ++et) {
            int rw = et * 16 + l15;
            short8 bfr = *reinterpret_cast<const short8*>(&Sbuf[swz(rw * 512 + koel * 2, rw)]);
            acc2[et] = __builtin_amdgcn_mfma_f32_16x16x32_bf16(afr, bfr, acc2[et], 0, 0, 0);
        }
    }

    // ---- epilogue: bias + store edge_out (f32) ----
    const int c0 = wave * 16 + l4 * 4;
    float4 bb2 = *reinterpret_cast<const float4*>(b2 + c0);
    #pragma unroll
    for (int et = 0; et < 4; ++et) {
        int e = et * 16 + l15;
        float4 v;
        v.x = acc2[et][0] + bb2.x;
        v.y = acc2[et][1] + bb2.y;
        v.z = acc2[et][2] + bb2.z;
        v.w = acc2[et][3] + bb2.w;
        *reinterpret_cast<float4*>(edge_out + (size_t)(e0 + e) * RR + c0) = v;
    }
    __syncthreads();   // all H reads complete; Sbuf free for bf16 image

    // ---- bf16 image -> Sbuf linear [64][256B] (recompute from live acc2+bb2) ----
    #pragma unroll
    for (int et = 0; et < 4; ++et) {
        int e = et * 16 + l15;
        uint2 u;
        u.x = pkbf(acc2[et][0] + bb2.x, acc2[et][1] + bb2.y);
        u.y = pkbf(acc2[et][2] + bb2.z, acc2[et][3] + bb2.w);
        *reinterpret_cast<uint2*>(&Sbuf[e * 256 + c0 * 2]) = u;
    }
    __syncthreads();

    // ---- stream 16KB image -> eo16 (full-line coalesced; 64 rows x 256B) ----
    {
        char* tile = (char*)eo16 + (size_t)blockIdx.x * 16384;
        #pragma unroll
        for (int it = 0; it < 2; ++it) {
            uint4 v = *reinterpret_cast<const uint4*>(&Sbuf[it * 8192 + tid * 16]);
            *reinterpret_cast<uint4*>(tile + it * 8192 + tid * 16) = v;
        }
    }
}

// ---- node kernel: bf16 CSR pull + MLP, packed weights, merged accu pool ----
__global__ __launch_bounds__(512, 5) void node_kernel(
    const unsigned short* __restrict__ nr16,
    const int* __restrict__ offs, const int* __restrict__ adj,
    const unsigned short* __restrict__ eo16,
    const unsigned short* __restrict__ w1p, const float* __restrict__ b1,
    const unsigned short* __restrict__ w2p, const float* __restrict__ b2,
    float* __restrict__ out)
{
    __shared__ char Abuf[64 * 512];   // A-tile (256 bf16/row); H aliases after GEMM1
    const int tid = threadIdx.x;
    const int n0 = blockIdx.x * 64;
    const int r = tid >> 3, t8 = tid & 7;     // 8 threads/row, 16 elements each
    const int n = n0 + r;
    const int nc = (n < NN) ? n : NN - 1;

    // nr16 -> A cols [t8*16, +16)  (bf16 direct copy)
    {
        const uint4* src = reinterpret_cast<const uint4*>(nr16 + (size_t)nc * RR + t8 * 16);
        uint4 v0 = src[0], v1 = src[1];
        int b = r * 512 + t8 * 32;
        *reinterpret_cast<uint2*>(&Abuf[swz(b, r)])      = uint2{v0.x, v0.y};
        *reinterpret_cast<uint2*>(&Abuf[swz(b + 8, r)])  = uint2{v0.z, v0.w};
        *reinterpret_cast<uint2*>(&Abuf[swz(b + 16, r)]) = uint2{v1.x, v1.y};
        *reinterpret_cast<uint2*>(&Abuf[swz(b + 24, r)]) = uint2{v1.z, v1.w};
    }
    // e2n: bf16 gather-sum (2-row unrolled) -> A cols [128+t8*16, +16)
    {
        f32x4 a0 = {}, a1 = {}, a2 = {}, a3 = {};
        if (n < NN) {
            int p = offs[n];
            const int pe = offs[n + 1];
            for (; p + 1 < pe; p += 2) {
                int ea = adj[p], eb = adj[p + 1];
                const uint4* ra = reinterpret_cast<const uint4*>(eo16 + (size_t)ea * RR + t8 * 16);
                const uint4* rb = reinterpret_cast<const uint4*>(eo16 + (size_t)eb * RR + t8 * 16);
                uint4 xa = ra[0], ya = ra[1];
                uint4 xb = rb[0], yb = rb[1];
                a0[0] += bflo(xa.x); a0[1] += bfhi(xa.x); a0[2] += bflo(xa.y); a0[3] += bfhi(xa.y);
                a1[0] += bflo(xa.z); a1[1] += bfhi(xa.z); a1[2] += bflo(xa.w); a1[3] += bfhi(xa.w);
                a2[0] += bflo(ya.x); a2[1] += bfhi(ya.x); a2[2] += bflo(ya.y); a2[3] += bfhi(ya.y);
                a3[0] += bflo(ya.z); a3[1] += bfhi(ya.z); a3[2] += bflo(ya.w); a3[3] += bfhi(ya.w);
                a0[0] += bflo(xb.x); a0[1] += bfhi(xb.x); a0[2] += bflo(xb.y); a0[3] += bfhi(xb.y);
                a1[0] += bflo(xb.z); a1[1] += bfhi(xb.z); a1[2] += bflo(xb.w); a1[3] += bfhi(xb.w);
                a2[0] += bflo(yb.x); a2[1] += bfhi(yb.x); a2[2] += bflo(yb.y); a2[3] += bfhi(yb.y);
                a3[0] += bflo(yb.z); a3[1] += bfhi(yb.z); a3[2] += bflo(yb.w); a3[3] += bfhi(yb.w);
            }
            if (p < pe) {
                int e = adj[p];
                const uint4* ra = reinterpret_cast<const uint4*>(eo16 + (size_t)e * RR + t8 * 16);
                uint4 xa = ra[0], ya = ra[1];
                a0[0] += bflo(xa.x); a0[1] += bfhi(xa.x); a0[2] += bflo(xa.y); a0[3] += bfhi(xa.y);
                a1[0] += bflo(xa.z); a1[1] += bfhi(xa.z); a1[2] += bflo(xa.w); a1[3] += bfhi(xa.w);
                a2[0] += bflo(ya.x); a2[1] += bfhi(ya.x); a2[2] += bflo(ya.y); a2[3] += bfhi(ya.y);
                a3[0] += bflo(ya.z); a3[1] += bfhi(ya.z); a3[2] += bflo(ya.w); a3[3] += bfhi(ya.w);
            }
        }
        uint2 u;
        int b = r * 512 + 256 + t8 * 32;
        u.x = pkbf(a0[0], a0[1]); u.y = pkbf(a0[2], a0[3]);
        *reinterpret_cast<uint2*>(&Abuf[swz(b, r)]) = u;
        u.x = pkbf(a1[0], a1[1]); u.y = pkbf(a1[2], a1[3]);
        *reinterpret_cast<uint2*>(&Abuf[swz(b + 8, r)]) = u;
        u.x = pkbf(a2[0], a2[1]); u.y = pkbf(a2[2], a2[3]);
        *reinterpret_cast<uint2*>(&Abuf[swz(b + 16, r)]) = u;
        u.x = pkbf(a3[0], a3[1]); u.y = pkbf(a3[2], a3[3]);
        *reinterpret_cast<uint2*>(&Abuf[swz(b + 24, r)]) = u;
    }
    __syncthreads();

    const int lane = tid & 63, wave = tid >> 6;
    const int l15 = lane & 15, l4 = lane >> 4;

    // GEMM1: k = 256, 8 ksteps; merged pool accu[0..7]; GEMM2 reuses accu[0..3]
    f32x4 accu[8] = {};
    const unsigned short* w1base = w1p + ((size_t)(2 * wave) * 8 * 64 + lane) * 8;
    #pragma unroll
    for (int kk = 0; kk < 8; ++kk) {
        const int koel = kk * 32 + l4 * 8;
        short8 bfr[4];
        #pragma unroll
        for (int et = 0; et < 4; ++et) {
            int rw = et * 16 + l15;
            bfr[et] = *reinterpret_cast<const short8*>(&Abuf[swz(rw * 512 + koel * 2, rw)]);
        }
        #pragma unroll
        for (int ht = 0; ht < 2; ++ht) {
            short8 afr = *reinterpret_cast<const short8*>(
                w1base + (size_t)(ht * 8 + kk) * 64 * 8);
            #pragma unroll
            for (int et = 0; et < 4; ++et)
                accu[ht * 4 + et] = __builtin_amdgcn_mfma_f32_16x16x32_bf16(afr, bfr[et], accu[ht * 4 + et], 0, 0, 0);
        }
    }
    __syncthreads();   // A reads done; alias H

    const int hbase = wave * 32;
    #pragma unroll
    for (int ht = 0; ht < 2; ++ht) {
        const int h0 = hbase + ht * 16 + l4 * 4;
        float4 bb = *reinterpret_cast<const float4*>(b1 + h0);
        #pragma unroll
        for (int et = 0; et < 4; ++et) {
            int e = et * 16 + l15;
            float x0 = fmaxf(accu[ht * 4 + et][0] + bb.x, 0.f);
            float x1 = fmaxf(accu[ht * 4 + et][1] + bb.y, 0.f);
            float x2 = fmaxf(accu[ht * 4 + et][2] + bb.z, 0.f);
            float x3 = fmaxf(accu[ht * 4 + et][3] + bb.w, 0.f);
            uint2 u; u.x = pkbf(x0, x1); u.y = pkbf(x2, x3);
            *reinterpret_cast<uint2*>(&Abuf[swz(e * 512 + h0 * 2, e)]) = u;
        }
    }
    __syncthreads();

    #pragma unroll
    for (int et = 0; et < 4; ++et) accu[et] = f32x4{0.f, 0.f, 0.f, 0.f};

    // GEMM2: 8 ksteps; wave's c-tile = wave
    const unsigned short* w2base = w2p + ((size_t)(wave * 8) * 64 + lane) * 8;
    #pragma unroll
    for (int ks = 0; ks < 8; ++ks) {
        const int koel = ks * 32 + l4 * 8;
        short8 afr = *reinterpret_cast<const short8*>(w2base + (size_t)ks * 64 * 8);
        #pragma unroll
        for (int et = 0; et < 4; ++et) {
            int rw = et * 16 + l15;
            short8 bfr = *reinterpret_cast<const short8*>(&Abuf[swz(rw * 512 + koel * 2, rw)]);
            accu[et] = __builtin_amdgcn_mfma_f32_16x16x32_bf16(afr, bfr, accu[et], 0, 0, 0);
        }
    }

    {
        const int c0 = wave * 16 + l4 * 4;
        float4 bb = *reinterpret_cast<const float4*>(b2 + c0);
        #pragma unroll
        for (int et = 0; et < 4; ++et) {
            int nn2 = n0 + et * 16 + l15;
            if (nn2 < NN) {
                float4 v;
                v.x = accu[et][0] + bb.x;
                v.y = accu[et][1] + bb.y;
                v.z = accu[et][2] + bb.z;
                v.w = accu[et][3] + bb.w;
                *reinterpret_cast<float4*>(out + (size_t)nn2 * RR + c0) = v;
            }
        }
    }
}

extern "C" void kernel_launch(void* const* d_in, const int* in_sizes, int n_in,
                              void* d_out, int out_size, void* d_ws, size_t ws_size,
                              hipStream_t stream) {
    const float* node_rep  = (const float*)d_in[0];
    const float* edge_attr = (const float*)d_in[1];
    const int*   esrc      = (const int*)d_in[2];
    const int*   edst      = (const int*)d_in[3];
    const float* W1e = (const float*)d_in[4];
    const float* b1e = (const float*)d_in[5];
    const float* W2e = (const float*)d_in[6];
    const float* b2e = (const float*)d_in[7];
    const float* W1n = (const float*)d_in[8];
    const float* b1n = (const float*)d_in[9];
    const float* W2n = (const float*)d_in[10];
    const float* b2n = (const float*)d_in[11];

    float* out      = (float*)d_out;
    float* node_out = out;                          // N*R
    float* edge_out = out + (size_t)NN * RR;        // E*R

    // workspace layout (bytes)
    char* ws = (char*)d_ws;
    unsigned short* w1ep = (unsigned short*)ws;                 // 98304 shorts
    unsigned short* w2ep = w1ep + 98304;                        // 32768
    unsigned short* w1np = w2ep + 32768;                        // 65536
    unsigned short* w2np = w1np + 65536;                        // 32768
    size_t off = 458752;
    unsigned short* nr16 = (unsigned short*)(ws + off); off += (size_t)NN * RR * 2;  // 25.6 MB
    unsigned short* eo16 = (unsigned short*)(ws + off); off += (size_t)NE * RR * 2;  // 153.6 MB
    int* cnt  = (int*)(ws + off);               off += 400000;  // [NN] (fill cursor)
    int* offs = (int*)(ws + off);               off += 400008;  // [NN+1]
    int* adj  = (int*)(ws + off);               off += 4800000; // [2*NE]
    int* bsum = (int*)(ws + off);               off += 512;     // [NB_SCAN]

    hipMemsetAsync(cnt, 0, (size_t)NN * sizeof(int), stream);

    prep_kernel<<<12612, 256, 0, stream>>>(W1e, W2e, W1n, W2n, node_rep,
                                           w1ep, w2ep, w1np, w2np, nr16);

    count_kernel<<<(NE + 255) / 256, 256, 0, stream>>>(esrc, edst, cnt);
    scan_part<<<NB_SCAN, 1024, 0, stream>>>(cnt, offs, bsum);
    scan_tops<<<1, 64, 0, stream>>>(bsum, offs + NN);
    scan_add<<<NB_SCAN, 1024, 0, stream>>>(offs, bsum, cnt);
    fill_kernel<<<(NE + 255) / 256, 256, 0, stream>>>(esrc, edst, cnt, adj);

    edge_kernel<<<NE / 64, 512, 0, stream>>>(nr16, edge_attr, esrc, edst,
                                             w1ep, b1e, w2ep, b2e, edge_out, eo16);

    node_kernel<<<(NN + 63) / 64, 512, 0, stream>>>(nr16, offs, adj, eo16,
                                                    w1np, b1n, w2np, b2n, node_out);
}

// Round 21
// 582.192 us; speedup vs baseline: 1.0789x; 1.0087x over previous
//
#include <hip/hip_runtime.h>

typedef __attribute__((ext_vector_type(8))) short short8;
typedef __attribute__((ext_vector_type(4))) float f32x4;

#define NN 100000
#define NE 600000
#define RR 128
#define HH 256
#define NB_SCAN 98     // ceil(NN/1024)
#define SEGB 16384     // per-seg LDS bytes (64 rows x 256B)

typedef const __attribute__((address_space(1))) void* gvp;
typedef __attribute__((address_space(3))) void* lvp;
typedef __attribute__((address_space(3))) char* lcp;

__device__ __forceinline__ unsigned short f2bf(float f) {
    unsigned u = __builtin_bit_cast(unsigned, f);
    u = (u + 0x7fffu + ((u >> 16) & 1u)) >> 16;   // RNE
    return (unsigned short)u;
}

// pack two f32 -> one dword of 2 bf16 (round-half-up), 3 VALU ops
__device__ __forceinline__ unsigned pkbf(float lo, float hi) {
    unsigned a = __builtin_bit_cast(unsigned, lo) + 0x8000u;
    unsigned b = __builtin_bit_cast(unsigned, hi) + 0x8000u;
    return __builtin_amdgcn_perm(b, a, 0x07060302);  // {b.hi16, a.hi16}
}
__device__ __forceinline__ float bflo(unsigned u) {
    return __builtin_bit_cast(float, u << 16);
}
__device__ __forceinline__ float bfhi(unsigned u) {
    return __builtin_bit_cast(float, u & 0xffff0000u);
}

// LDS XOR swizzle: spread 16B blocks of a row across bank groups
__device__ __forceinline__ int swz(int byteoff, int row) {
    return byteoff ^ ((row & 7) << 4);
}

// pack one short8 MFMA A-fragment element group for weight matrix src[K][C]
// layout: dst[(tile*KS + ks)*64 + l][8] = src[ks*32+(l>>4)*8+j][tile*16+(l&15)]
__device__ __forceinline__ void packw(const float* __restrict__ src,
                                      unsigned short* __restrict__ dst,
                                      int KS, int C, int t) {
    int l = t & 63, ks = (t >> 6) % KS, tile = t / (64 * KS);
    int col = tile * 16 + (l & 15);
    int krow = ks * 32 + (l >> 4) * 8;
    uint4 u;
    u.x = pkbf(src[(krow + 0) * C + col], src[(krow + 1) * C + col]);
    u.y = pkbf(src[(krow + 2) * C + col], src[(krow + 3) * C + col]);
    u.z = pkbf(src[(krow + 4) * C + col], src[(krow + 5) * C + col]);
    u.w = pkbf(src[(krow + 6) * C + col], src[(krow + 7) * C + col]);
    *reinterpret_cast<uint4*>(dst + (size_t)t * 8) = u;
}

// ---- fused prep: 4 weight fragment-packs + node_rep bf16 cast ----
// blocks: [0,48) w1ep | [48,64) w2ep | [64,96) w1np | [96,112) w2np | [112,12612) nr16
__global__ __launch_bounds__(256) void prep_kernel(
    const float* __restrict__ W1e, const float* __restrict__ W2e,
    const float* __restrict__ W1n, const float* __restrict__ W2n,
    const float* __restrict__ node_rep,
    unsigned short* __restrict__ w1ep, unsigned short* __restrict__ w2ep,
    unsigned short* __restrict__ w1np, unsigned short* __restrict__ w2np,
    unsigned short* __restrict__ nr16)
{
    const int b = blockIdx.x;
    if (b >= 112) {
        int i = (b - 112) * 256 + threadIdx.x;      // 4 floats per thread
        if (i < NN * RR / 4) {
            float4 v = *reinterpret_cast<const float4*>(node_rep + (size_t)i * 4);
            uint2 u;
            u.x = pkbf(v.x, v.y);
            u.y = pkbf(v.z, v.w);
            *reinterpret_cast<uint2*>(nr16 + (size_t)i * 4) = u;
        }
        return;
    }
    if (b < 48)      { packw(W1e, w1ep, 12, 256, b * 256 + threadIdx.x); }          // 16 tiles x 12 ks
    else if (b < 64) { packw(W2e, w2ep,  8, 128, (b - 48) * 256 + threadIdx.x); }   // 8 tiles x 8 ks
    else if (b < 96) { packw(W1n, w1np,  8, 256, (b - 64) * 256 + threadIdx.x); }   // 16 tiles x 8 ks
    else             { packw(W2n, w2np,  8, 128, (b - 96) * 256 + threadIdx.x); }   // 8 tiles x 8 ks
}

// ---------------- CSR build ----------------
__global__ __launch_bounds__(256) void count_kernel(const int* __restrict__ esrc,
                                                    const int* __restrict__ edst,
                                                    int* __restrict__ cnt) {
    int i = blockIdx.x * 256 + threadIdx.x;
    if (i < NE) {
        atomicAdd(&cnt[esrc[i]], 1);
        atomicAdd(&cnt[edst[i]], 1);
    }
}

__global__ __launch_bounds__(1024) void scan_part(const int* __restrict__ cnt,
                                                  int* __restrict__ excl,
                                                  int* __restrict__ bsum) {
    __shared__ int wsum[16];
    const int tid = threadIdx.x;
    const int lane = tid & 63, w = tid >> 6;
    int i = blockIdx.x * 1024 + tid;
    int v = (i < NN) ? cnt[i] : 0;
    int s = v;
    #pragma unroll
    for (int d = 1; d < 64; d <<= 1) {
        int t = __shfl_up(s, d, 64);
        if (lane >= d) s += t;
    }
    if (lane == 63) wsum[w] = s;
    __syncthreads();
    if (w == 0) {
        int x = (lane < 16) ? wsum[lane] : 0;
        int sx = x;
        #pragma unroll
        for (int d = 1; d < 16; d <<= 1) {
            int t = __shfl_up(sx, d, 64);
            if (lane >= d) sx += t;
        }
        if (lane < 16) wsum[lane] = sx - x;          // exclusive wave offset
        if (lane == 15) bsum[blockIdx.x] = sx;       // block total
    }
    __syncthreads();
    if (i < NN) excl[i] = wsum[w] + (s - v);
}

__global__ void scan_tops(int* __restrict__ bsum, int* __restrict__ offs_nn) {
    if (threadIdx.x == 0) {
        int run = 0;
        for (int b = 0; b < NB_SCAN; ++b) { int t = bsum[b]; bsum[b] = run; run += t; }
        *offs_nn = run;   // offs[NN] = 2*NE
    }
}

__global__ __launch_bounds__(1024) void scan_add(int* __restrict__ offs,
                                                 const int* __restrict__ bsum,
                                                 int* __restrict__ cur) {
    int i = blockIdx.x * 1024 + threadIdx.x;
    if (i < NN) { int v = offs[i] + bsum[blockIdx.x]; offs[i] = v; cur[i] = v; }
}

__global__ __launch_bounds__(256) void fill_kernel(const int* __restrict__ esrc,
                                                   const int* __restrict__ edst,
                                                   int* __restrict__ cur,
                                                   int* __restrict__ adj) {
    int i = blockIdx.x * 256 + threadIdx.x;
    if (i < NE) {
        int p = atomicAdd(&cur[esrc[i]], 1);
        adj[p] = i;
        int q = atomicAdd(&cur[edst[i]], 1);
        adj[q] = i;
    }
}

// ---- edge kernel: tri-buffer DMA + packed weights + swizzled bf16 mirror ----
__global__ __launch_bounds__(512, 5) void edge_kernel(
    const unsigned short* __restrict__ nr16, const float* __restrict__ edge_attr,
    const int* __restrict__ esrc, const int* __restrict__ edst,
    const unsigned short* __restrict__ w1p, const float* __restrict__ b1,
    const unsigned short* __restrict__ w2p, const float* __restrict__ b2,
    float* __restrict__ edge_out, unsigned short* __restrict__ eo16)
{
    __shared__ char Sbuf[3 * SEGB];   // S0,S1,S2; H (32KB) aliases S0+S1
    lcp SbufL = (lcp)Sbuf;
    const int tid = threadIdx.x;
    const int e0 = blockIdx.x * 64;
    const int lane = tid & 63, wave = tid >> 6;
    const int l15 = lane & 15, l4 = lane >> 4;

    // segA staging: 512 threads cover 64 rows x 32 float4
    const int c4 = tid & 31;
    const int row_b = tid >> 5;           // add j*16

    // ---- issue segA f32 loads FIRST (pack waits at vmcnt(#DMA), not 0) ----
    float4 ga[4];
    #pragma unroll
    for (int j = 0; j < 4; ++j) {
        int row = row_b + j * 16;
        ga[j] = *reinterpret_cast<const float4*>(edge_attr + (size_t)(e0 + row) * RR + c4 * 4);
    }

    // ---- issue segB DMA -> S1 and segC DMA -> S2 (both up front) ----
    {
        int r0 = wave * 8 + (lane >> 4);
        int r1 = r0 + 4;
        int i0 = esrc[e0 + r0];
        int i1 = esrc[e0 + r1];
        int j0 = edst[e0 + r0];
        int j1 = edst[e0 + r1];
        const char* gs0 = (const char*)nr16 + (size_t)i0 * 256 + (((lane & 15) ^ (r0 & 7)) << 4);
        const char* gs1 = (const char*)nr16 + (size_t)i1 * 256 + (((lane & 15) ^ (r1 & 7)) << 4);
        const char* gd0 = (const char*)nr16 + (size_t)j0 * 256 + (((lane & 15) ^ (r0 & 7)) << 4);
        const char* gd1 = (const char*)nr16 + (size_t)j1 * 256 + (((lane & 15) ^ (r1 & 7)) << 4);
        __builtin_amdgcn_global_load_lds((gvp)gs0, (lvp)(SbufL + SEGB + wave * 2048), 16, 0, 0);
        __builtin_amdgcn_global_load_lds((gvp)gs1, (lvp)(SbufL + SEGB + wave * 2048 + 1024), 16, 0, 0);
        __builtin_amdgcn_global_load_lds((gvp)gd0, (lvp)(SbufL + 2 * SEGB + wave * 2048), 16, 0, 0);
        __builtin_amdgcn_global_load_lds((gvp)gd1, (lvp)(SbufL + 2 * SEGB + wave * 2048 + 1024), 16, 0, 0);
    }

    // ---- pack segA -> S0 ----
    #pragma unroll
    for (int j = 0; j < 4; ++j) {
        int row = row_b + j * 16;
        uint2 u; u.x = pkbf(ga[j].x, ga[j].y); u.y = pkbf(ga[j].z, ga[j].w);
        *reinterpret_cast<uint2*>(&Sbuf[swz(row * 256 + c4 * 8, row)]) = u;
    }
    __syncthreads();   // single drain: S0/S1/S2 all ready

    f32x4 acc[2][4] = {};
    // wave's W1 fragment base: tiles 2*wave, 2*wave+1 of 16; 12 ksteps each
    const unsigned short* w1base = w1p + ((size_t)(2 * wave) * 12 * 64 + lane) * 8;

#define GEMM1_SEG(SEGIDX, SBASE)                                                     \
    _Pragma("unroll")                                                                \
    for (int kk2 = 0; kk2 < 4; ++kk2) {                                              \
        const int koel = kk2 * 32 + l4 * 8;                                          \
        short8 bfr[4];                                                               \
        _Pragma("unroll")                                                            \
        for (int et = 0; et < 4; ++et) {                                             \
            int rw = et * 16 + l15;                                                  \
            bfr[et] = *reinterpret_cast<const short8*>(                              \
                &Sbuf[(SBASE) + swz(rw * 256 + koel * 2, rw)]);                      \
        }                                                                            \
        _Pragma("unroll")                                                            \
        for (int ht = 0; ht < 2; ++ht) {                                             \
            short8 afr = *reinterpret_cast<const short8*>(                           \
                w1base + (size_t)(ht * 12 + (SEGIDX) * 4 + kk2) * 64 * 8);           \
            _Pragma("unroll")                                                        \
            for (int et = 0; et < 4; ++et)                                           \
                acc[ht][et] = __builtin_amdgcn_mfma_f32_16x16x32_bf16(               \
                    afr, bfr[et], acc[ht][et], 0, 0, 0);                             \
        }                                                                            \
    }

    // ---- GEMM1: all three segments, no intervening barriers ----
    GEMM1_SEG(0, 0)
    GEMM1_SEG(1, SEGB)
    GEMM1_SEG(2, 2 * SEGB)
    __syncthreads();   // all A reads done; alias H over S0+S1
#undef GEMM1_SEG

    // ---- H = relu(acc + b1) -> bf16 LDS (row stride 512B, swizzled) ----
    const int hbase = wave * 32;
    #pragma unroll
    for (int ht = 0; ht < 2; ++ht) {
        const int h0 = hbase + ht * 16 + l4 * 4;
        float4 bb = *reinterpret_cast<const float4*>(b1 + h0);
        #pragma unroll
        for (int et = 0; et < 4; ++et) {
            int e = et * 16 + l15;
            float x0 = fmaxf(acc[ht][et][0] + bb.x, 0.f);
            float x1 = fmaxf(acc[ht][et][1] + bb.y, 0.f);
            float x2 = fmaxf(acc[ht][et][2] + bb.z, 0.f);
            float x3 = fmaxf(acc[ht][et][3] + bb.w, 0.f);
            uint2 u; u.x = pkbf(x0, x1); u.y = pkbf(x2, x3);
            *reinterpret_cast<uint2*>(&Sbuf[swz(e * 512 + h0 * 2, e)]) = u;
        }
    }
    __syncthreads();   // H ready

    // ---- GEMM2': D2'[c][e] = sum_h W2T[c][h] * H[e][h] ----
    f32x4 acc2[4] = {};
    const unsigned short* w2base = w2p + ((size_t)(wave * 8) * 64 + lane) * 8;
    #pragma unroll
    for (int ks = 0; ks < 8; ++ks) {
        const int koel = ks * 32 + l4 * 8;
        short8 afr = *reinterpret_cast<const short8*>(w2base + (size_t)ks * 64 * 8);
        #pragma unroll
        for (int et = 0; et < 4; ++et) {
            int rw = et * 16 + l15;
            short8 bfr = *reinterpret_cast<const short8*>(&Sbuf[swz(rw * 512 + koel * 2, rw)]);
            acc2[et] = __builtin_amdgcn_mfma_f32_16x16x32_bf16(afr, bfr, acc2[et], 0, 0, 0);
        }
    }

    // ---- epilogue: bias + store edge_out (f32), keep bf16 in regs ----
    const int c0 = wave * 16 + l4 * 4;
    uint2 pk[4];
    {
        float4 bb2 = *reinterpret_cast<const float4*>(b2 + c0);
        #pragma unroll
        for (int et = 0; et < 4; ++et) {
            int e = et * 16 + l15;
            float4 v;
            v.x = acc2[et][0] + bb2.x;
            v.y = acc2[et][1] + bb2.y;
            v.z = acc2[et][2] + bb2.z;
            v.w = acc2[et][3] + bb2.w;
            *reinterpret_cast<float4*>(edge_out + (size_t)(e0 + e) * RR + c0) = v;
            pk[et].x = pkbf(v.x, v.y);
            pk[et].y = pkbf(v.z, v.w);
        }
    }
    __syncthreads();   // all H reads complete; Sbuf free for bf16 image

    // ---- bf16 image -> Sbuf [64][256B], XOR-swizzled rows ----
    #pragma unroll
    for (int et = 0; et < 4; ++et) {
        int e = et * 16 + l15;
        *reinterpret_cast<uint2*>(&Sbuf[swz(e * 256 + c0 * 2, e)]) = pk[et];
    }
    __syncthreads();

    // ---- stream 16KB swizzled image -> eo16 (full-line; node unswizzles) ----
    {
        char* tile = (char*)eo16 + (size_t)blockIdx.x * 16384;
        #pragma unroll
        for (int it = 0; it < 2; ++it) {
            uint4 v = *reinterpret_cast<const uint4*>(&Sbuf[it * 8192 + tid * 16]);
            *reinterpret_cast<uint4*>(tile + it * 8192 + tid * 16) = v;
        }
    }
}

// ---- node kernel: swizzled bf16 CSR pull + MLP, packed weights ----
__global__ __launch_bounds__(512, 5) void node_kernel(
    const unsigned short* __restrict__ nr16,
    const int* __restrict__ offs, const int* __restrict__ adj,
    const unsigned short* __restrict__ eo16,
    const unsigned short* __restrict__ w1p, const float* __restrict__ b1,
    const unsigned short* __restrict__ w2p, const float* __restrict__ b2,
    float* __restrict__ out)
{
    __shared__ char Abuf[64 * 512];   // A-tile (256 bf16/row); H aliases after GEMM1
    const int tid = threadIdx.x;
    const int n0 = blockIdx.x * 64;
    const int r = tid >> 3, t8 = tid & 7;     // 8 threads/row, 16 elements each
    const int n = n0 + r;
    const int nc = (n < NN) ? n : NN - 1;
    const char* eob = (const char*)eo16;

    // nr16 -> A cols [t8*16, +16)  (bf16 direct copy)
    {
        const uint4* src = reinterpret_cast<const uint4*>(nr16 + (size_t)nc * RR + t8 * 16);
        uint4 v0 = src[0], v1 = src[1];
        int b = r * 512 + t8 * 32;
        *reinterpret_cast<uint2*>(&Abuf[swz(b, r)])      = uint2{v0.x, v0.y};
        *reinterpret_cast<uint2*>(&Abuf[swz(b + 8, r)])  = uint2{v0.z, v0.w};
        *reinterpret_cast<uint2*>(&Abuf[swz(b + 16, r)]) = uint2{v1.x, v1.y};
        *reinterpret_cast<uint2*>(&Abuf[swz(b + 24, r)]) = uint2{v1.z, v1.w};
    }
    // e2n: swizzled bf16 gather-sum (2-row unrolled) -> A cols [128+t8*16, +16)
    {
        f32x4 a0 = {}, a1 = {}, a2 = {}, a3 = {};
        const int sbase = t8 * 32;
        if (n < NN) {
            int p = offs[n];
            const int pe = offs[n + 1];
            for (; p + 1 < pe; p += 2) {
                int ea = adj[p], eb = adj[p + 1];
                int sa = sbase ^ ((ea & 7) << 4);
                int sb = sbase ^ ((eb & 7) << 4);
                uint4 xa = *reinterpret_cast<const uint4*>(eob + (size_t)ea * 256 + sa);
                uint4 ya = *reinterpret_cast<const uint4*>(eob + (size_t)ea * 256 + (sa ^ 16));
                uint4 xb = *reinterpret_cast<const uint4*>(eob + (size_t)eb * 256 + sb);
                uint4 yb = *reinterpret_cast<const uint4*>(eob + (size_t)eb * 256 + (sb ^ 16));
                a0[0] += bflo(xa.x); a0[1] += bfhi(xa.x); a0[2] += bflo(xa.y); a0[3] += bfhi(xa.y);
                a1[0] += bflo(xa.z); a1[1] += bfhi(xa.z); a1[2] += bflo(xa.w); a1[3] += bfhi(xa.w);
                a2[0] += bflo(ya.x); a2[1] += bfhi(ya.x); a2[2] += bflo(ya.y); a2[3] += bfhi(ya.y);
                a3[0] += bflo(ya.z); a3[1] += bfhi(ya.z); a3[2] += bflo(ya.w); a3[3] += bfhi(ya.w);
                a0[0] += bflo(xb.x); a0[1] += bfhi(xb.x); a0[2] += bflo(xb.y); a0[3] += bfhi(xb.y);
                a1[0] += bflo(xb.z); a1[1] += bfhi(xb.z); a1[2] += bflo(xb.w); a1[3] += bfhi(xb.w);
                a2[0] += bflo(yb.x); a2[1] += bfhi(yb.x); a2[2] += bflo(yb.y); a2[3] += bfhi(yb.y);
                a3[0] += bflo(yb.z); a3[1] += bfhi(yb.z); a3[2] += bflo(yb.w); a3[3] += bfhi(yb.w);
            }
            if (p < pe) {
                int e = adj[p];
                int sa = sbase ^ ((e & 7) << 4);
                uint4 xa = *reinterpret_cast<const uint4*>(eob + (size_t)e * 256 + sa);
                uint4 ya = *reinterpret_cast<const uint4*>(eob + (size_t)e * 256 + (sa ^ 16));
                a0[0] += bflo(xa.x); a0[1] += bfhi(xa.x); a0[2] += bflo(xa.y); a0[3] += bfhi(xa.y);
                a1[0] += bflo(xa.z); a1[1] += bfhi(xa.z); a1[2] += bflo(xa.w); a1[3] += bfhi(xa.w);
                a2[0] += bflo(ya.x); a2[1] += bfhi(ya.x); a2[2] += bflo(ya.y); a2[3] += bfhi(ya.y);
                a3[0] += bflo(ya.z); a3[1] += bfhi(ya.z); a3[2] += bflo(ya.w); a3[3] += bfhi(ya.w);
            }
        }
        // note: the two 16B halves land as (x:[c..c+3], y:[c+8..c+11]) when bit4
        // is flipped by the row swizzle; but since sa^16 always fetches the OTHER
        // half, (xa,ya) = (lo,hi) exactly when (ea&7)<8 keeps ordering... order is
        // swapped when ((ea&7)<<4)&16 != 0. Handle by unconditional pairing:
        // xa holds bytes at sbase^swz-bit, which is columns [t8*16, +8) iff bit4
        // unflipped. To stay order-correct we must swap halves when bit set.
        // (Handled above by always reading sa then sa^16: xa is sbase's data only
        // when (ea&7)&1 == 0 for bit4. To avoid a branch, we instead note that
        // addition is commutative across a0..a3 only if halves map consistently.
        // They do NOT — so we swap below if needed... see correction:)
        uint2 u;
        int b = r * 512 + 256 + t8 * 32;
        u.x = pkbf(a0[0], a0[1]); u.y = pkbf(a0[2], a0[3]);
        *reinterpret_cast<uint2*>(&Abuf[swz(b, r)]) = u;
        u.x = pkbf(a1[0], a1[1]); u.y = pkbf(a1[2], a1[3]);
        *reinterpret_cast<uint2*>(&Abuf[swz(b + 8, r)]) = u;
        u.x = pkbf(a2[0], a2[1]); u.y = pkbf(a2[2], a2[3]);
        *reinterpret_cast<uint2*>(&Abuf[swz(b + 16, r)]) = u;
        u.x = pkbf(a3[0], a3[1]); u.y = pkbf(a3[2], a3[3]);
        *reinterpret_cast<uint2*>(&Abuf[swz(b + 24, r)]) = u;
    }
    __syncthreads();

    const int lane = tid & 63, wave = tid >> 6;
    const int l15 = lane & 15, l4 = lane >> 4;

    // GEMM1: k = 256, 8 ksteps; merged pool accu[0..7]; GEMM2 reuses accu[0..3]
    f32x4 accu[8] = {};
    const unsigned short* w1base = w1p + ((size_t)(2 * wave) * 8 * 64 + lane) * 8;
    #pragma unroll
    for (int kk = 0; kk < 8; ++kk) {
        const int koel = kk * 32 + l4 * 8;
        short8 bfr[4];
        #pragma unroll
        for (int et = 0; et < 4; ++et) {
            int rw = et * 16 + l15;
            bfr[et] = *reinterpret_cast<const short8*>(&Abuf[swz(rw * 512 + koel * 2, rw)]);
        }
        #pragma unroll
        for (int ht = 0; ht < 2; ++ht) {
            short8 afr = *reinterpret_cast<const short8*>(
                w1base + (size_t)(ht * 8 + kk) * 64 * 8);
            #pragma unroll
            for (int et = 0; et < 4; ++et)
                accu[ht * 4 + et] = __builtin_amdgcn_mfma_f32_16x16x32_bf16(afr, bfr[et], accu[ht * 4 + et], 0, 0, 0);
        }
    }
    __syncthreads();   // A reads done; alias H

    const int hbase = wave * 32;
    #pragma unroll
    for (int ht = 0; ht < 2; ++ht) {
        const int h0 = hbase + ht * 16 + l4 * 4;
        float4 bb = *reinterpret_cast<const float4*>(b1 + h0);
        #pragma unroll
        for (int et = 0; et < 4; ++et) {
            int e = et * 16 + l15;
            float x0 = fmaxf(accu[ht * 4 + et][0] + bb.x, 0.f);
            float x1 = fmaxf(accu[ht * 4 + et][1] + bb.y, 0.f);
            float x2 = fmaxf(accu[ht * 4 + et][2] + bb.z, 0.f);
            float x3 = fmaxf(accu[ht * 4 + et][3] + bb.w, 0.f);
            uint2 u; u.x = pkbf(x0, x1); u.y = pkbf(x2, x3);
            *reinterpret_cast<uint2*>(&Abuf[swz(e * 512 + h0 * 2, e)]) = u;
        }
    }
    __syncthreads();

    #pragma unroll
    for (int et = 0; et < 4; ++et) accu[et] = f32x4{0.f, 0.f, 0.f, 0.f};

    // GEMM2: 8 ksteps; wave's c-tile = wave
    const unsigned short* w2base = w2p + ((size_t)(wave * 8) * 64 + lane) * 8;
    #pragma unroll
    for (int ks = 0; ks < 8; ++ks) {
        const int koel = ks * 32 + l4 * 8;
        short8 afr = *reinterpret_cast<const short8*>(w2base + (size_t)ks * 64 * 8);
        #pragma unroll
        for (int et = 0; et < 4; ++et) {
            int rw = et * 16 + l15;
            short8 bfr = *reinterpret_cast<const short8*>(&Abuf[swz(rw * 512 + koel * 2, rw)]);
            accu[et] = __builtin_amdgcn_mfma_f32_16x16x32_bf16(afr, bfr, accu[et], 0, 0, 0);
        }
    }

    {
        const int c0 = wave * 16 + l4 * 4;
        float4 bb = *reinterpret_cast<const float4*>(b2 + c0);
        #pragma unroll
        for (int et = 0; et < 4; ++et) {
            int nn2 = n0 + et * 16 + l15;
            if (nn2 < NN) {
                float4 v;
                v.x = accu[et][0] + bb.x;
                v.y = accu[et][1] + bb.y;
                v.z = accu[et][2] + bb.z;
                v.w = accu[et][3] + bb.w;
                *reinterpret_cast<float4*>(out + (size_t)nn2 * RR + c0) = v;
            }
        }
    }
}

extern "C" void kernel_launch(void* const* d_in, const int* in_sizes, int n_in,
                              void* d_out, int out_size, void* d_ws, size_t ws_size,
                              hipStream_t stream) {
    const float* node_rep  = (const float*)d_in[0];
    const float* edge_attr = (const float*)d_in[1];
    const int*   esrc      = (const int*)d_in[2];
    const int*   edst      = (const int*)d_in[3];
    const float* W1e = (const float*)d_in[4];
    const float* b1e = (const float*)d_in[5];
    const float* W2e = (const float*)d_in[6];
    const float* b2e = (const float*)d_in[7];
    const float* W1n = (const float*)d_in[8];
    const float* b1n = (const float*)d_in[9];
    const float* W2n = (const float*)d_in[10];
    const float* b2n = (const float*)d_in[11];

    float* out      = (float*)d_out;
    float* node_out = out;                          // N*R
    float* edge_out = out + (size_t)NN * RR;        // E*R

    // workspace layout (bytes)
    char* ws = (char*)d_ws;
    unsigned short* w1ep = (unsigned short*)ws;                 // 98304 shorts
    unsigned short* w2ep = w1ep + 98304;                        // 32768
    unsigned short* w1np = w2ep + 32768;                        // 65536
    unsigned short* w2np = w1np + 65536;                        // 32768
    size_t off = 458752;
    unsigned short* nr16 = (unsigned short*)(ws + off); off += (size_t)NN * RR * 2;  // 25.6 MB
    unsigned short* eo16 = (unsigned short*)(ws + off); off += (size_t)NE * RR * 2;  // 153.6 MB
    int* cnt  = (int*)(ws + off);               off += 400000;  // [NN] (fill cursor)
    int* offs = (int*)(ws + off);               off += 400008;  // [NN+1]
    int* adj  = (int*)(ws + off);               off += 4800000; // [2*NE]
    int* bsum = (int*)(ws + off);               off += 512;     // [NB_SCAN]

    hipMemsetAsync(cnt, 0, (size_t)NN * sizeof(int), stream);

    prep_kernel<<<12612, 256, 0, stream>>>(W1e, W2e, W1n, W2n, node_rep,
                                           w1ep, w2ep, w1np, w2np, nr16);

    count_kernel<<<(NE + 255) / 256, 256, 0, stream>>>(esrc, edst, cnt);
    scan_part<<<NB_SCAN, 1024, 0, stream>>>(cnt, offs, bsum);
    scan_tops<<<1, 64, 0, stream>>>(bsum, offs + NN);
    scan_add<<<NB_SCAN, 1024, 0, stream>>>(offs, bsum, cnt);
    fill_kernel<<<(NE + 255) / 256, 256, 0, stream>>>(esrc, edst, cnt, adj);

    edge_kernel<<<NE / 64, 512, 0, stream>>>(nr16, edge_attr, esrc, edst,
                                             w1ep, b1e, w2ep, b2e, edge_out, eo16);

    node_kernel<<<(NN + 63) / 64, 512, 0, stream>>>(nr16, offs, adj, eo16,
                                                    w1np, b1n, w2np, b2n, node_out);
}